// Round 9
// baseline (271.824 us; speedup 1.0000x reference)
//
#include <hip/hip_runtime.h>
#include <hip/hip_bf16.h>
#include <math.h>

typedef __hip_bfloat16 bf16;
typedef __attribute__((ext_vector_type(4))) float v_f32x4;
typedef __attribute__((ext_vector_type(4))) unsigned short v_u16x4;
typedef __attribute__((ext_vector_type(8))) unsigned short v_u16x8;
typedef __attribute__((ext_vector_type(8))) __bf16 v_bf16x8;
typedef __attribute__((ext_vector_type(4))) __bf16 v_bf16x4;
typedef __attribute__((ext_vector_type(4))) short v_s16x4;

#define NB 2
#define NT 2048
#define ND 1024
#define NH 16
#define NSC 64
#define NST 16
#define NM (NB*NT)
#define RMS_EPS 1.1920929e-07f
#define NCHUNK 32
#define CLEN 64

__device__ inline float b2f(unsigned short u) {
  union { unsigned int i; float f; } v; v.i = ((unsigned int)u) << 16; return v.f;
}
__device__ inline unsigned short f2b(float f) {  // RNE f32->bf16
  union { float f; unsigned int i; } v; v.f = f;
  unsigned int r = (v.i + 0x7FFF + ((v.i >> 16) & 1)) >> 16;
  return (unsigned short)r;
}

// K=16 bf16 MFMA with builtin-name fallback
__device__ inline v_f32x4 mfma16(v_bf16x4 a, v_bf16x4 b, v_f32x4 c) {
#if __has_builtin(__builtin_amdgcn_mfma_f32_16x16x16_bf16)
  return __builtin_amdgcn_mfma_f32_16x16x16_bf16(a, b, c, 0, 0, 0);
#else
  union U { v_bf16x4 h; v_s16x4 s; };
  U ua, ub; ua.h = a; ub.h = b;
  return __builtin_amdgcn_mfma_f32_16x16x16bf16_1k(ua.s, ub.s, c, 0, 0, 0);
#endif
}

// async global->LDS, 16B per lane; LDS dest = wave-uniform base + lane*16
__device__ inline void gl_lds16(const bf16* g, bf16* l) {
  __builtin_amdgcn_global_load_lds((__attribute__((address_space(1))) void*)g,
                                   (__attribute__((address_space(3))) void*)l,
                                   16, 0, 0);
}

// ---------------- fused: all weight cvt (blocks 0..4294) + rmsnorm1 (blocks 4295..8390) ----------------
__global__ __launch_bounds__(256) void cvt_rms_kernel(
    const float* __restrict__ qkv_w, const float* __restrict__ o_w,
    const float* __restrict__ out_w, const float* __restrict__ in_w,
    const float* __restrict__ gate_w, const float* __restrict__ dt_w,
    const float* __restrict__ Bp_w, const float* __restrict__ Cp_w,
    bf16* __restrict__ qkvw_b, bf16* __restrict__ ow_b, bf16* __restrict__ outw_b,
    bf16* __restrict__ W1, bf16* __restrict__ W2,
    const float* __restrict__ x, const float* __restrict__ n1w, bf16* __restrict__ h) {
  const int blk = blockIdx.x, t = threadIdx.x;
  if (blk >= 4295) {  // rmsnorm1 of x row -> h
    const int row = blk - 4295;
    v_f32x4 xv = *(const v_f32x4*)(x + (size_t)row * ND + t * 4);
    float s = xv[0]*xv[0] + xv[1]*xv[1] + xv[2]*xv[2] + xv[3]*xv[3];
    #pragma unroll
    for (int off = 32; off; off >>= 1) s += __shfl_xor(s, off, 64);
    __shared__ float red[4];
    __shared__ float scale_s;
    if ((t & 63) == 0) red[t >> 6] = s;
    __syncthreads();
    if (t == 0) scale_s = rsqrtf((red[0] + red[1] + red[2] + red[3]) * (1.0f / ND) + RMS_EPS);
    __syncthreads();
    float sc = scale_s;
    v_f32x4 wv = *(const v_f32x4*)(n1w + t * 4);
    v_u16x4 o;
    o[0] = f2b(xv[0] * sc * wv[0]);
    o[1] = f2b(xv[1] * sc * wv[1]);
    o[2] = f2b(xv[2] * sc * wv[2]);
    o[3] = f2b(xv[3] * sc * wv[3]);
    *(v_u16x4*)((unsigned short*)h + (size_t)row * ND + t * 4) = o;
    return;
  }
  const float* src; bf16* dst; int base;
  if (blk < 3072)      { src = qkv_w;  dst = qkvw_b;      base = blk; }
  else if (blk < 4096) { src = o_w;    dst = ow_b;        base = blk - 3072; }
  else if (blk < 4160) { src = out_w;  dst = outw_b;      base = blk - 4096; }
  else if (blk < 4224) { src = in_w;   dst = W1;          base = blk - 4160; }
  else if (blk < 4288) { src = gate_w; dst = W1 + 65536;  base = blk - 4224; }
  else if (blk < 4292) { src = dt_w;   dst = W2;          base = blk - 4288; }
  else if (blk == 4292){ src = Bp_w;   dst = W2 + 4096;   base = 0; }
  else if (blk == 4293){ src = Cp_w;   dst = W2 + 5120;   base = 0; }
  else {  // zero tail of W2 (rows 96..127)
    v_u16x8 z;
    #pragma unroll
    for (int i = 0; i < 8; i++) z[i] = 0;
    *(v_u16x8*)(W2 + 6144 + t * 8) = z;
    return;
  }
  int i = base * 256 + t;
  v_f32x4 v = ((const v_f32x4*)src)[i];
  v_u16x4 o;
  o[0] = f2b(v[0]); o[1] = f2b(v[1]); o[2] = f2b(v[2]); o[3] = f2b(v[3]);
  ((v_u16x4*)dst)[i] = o;
}

// ---------------- GEMM 128x128; VT=true: V-region blocks write VtG transposed ----------------
template <bool RES, bool OUTF32, bool VT>
__global__ __launch_bounds__(256) void gemm_bt_kernel(
    const bf16* __restrict__ A, const bf16* __restrict__ Bw,
    const float* __restrict__ res, void* __restrict__ Cout, int N, int K, int lda,
    bf16* __restrict__ VtG) {
  __shared__ alignas(16) bf16 As[128 * 32];
  __shared__ alignas(16) bf16 Bs[128 * 32];
  const int tid = threadIdx.x;
  const int wid = tid >> 6;
  const int lane = tid & 63;
  const int c = lane & 15;
  const int quad = lane >> 4;
  const int m0 = blockIdx.y * 128;
  const int n0 = blockIdx.x * 128;
  const int wm = (wid >> 1) * 64;
  const int wn = (wid & 1) * 64;
  const int srow = tid >> 2;
  const int schunk = tid & 3;

  const bf16* Ap0 = A + (size_t)(m0 + srow) * lda + schunk * 8;
  const bf16* Ap1 = Ap0 + (size_t)64 * lda;
  const bf16* Bp0 = Bw + (size_t)(n0 + srow) * K + schunk * 8;
  const bf16* Bp1 = Bp0 + (size_t)64 * K;
  bf16* AsW0 = As + wid * 512;
  bf16* AsW1 = As + 2048 + wid * 512;
  bf16* BsW0 = Bs + wid * 512;
  bf16* BsW1 = Bs + 2048 + wid * 512;

  v_f32x4 acc[4][4];
  #pragma unroll
  for (int i = 0; i < 4; i++)
    #pragma unroll
    for (int j = 0; j < 4; j++)
      #pragma unroll
      for (int r = 0; r < 4; r++) acc[i][j][r] = 0.0f;

  const int nk = K >> 5;
  for (int kt = 0; kt < nk; kt++) {
    gl_lds16(Ap0 + kt * 32, AsW0);
    gl_lds16(Ap1 + kt * 32, AsW1);
    gl_lds16(Bp0 + kt * 32, BsW0);
    gl_lds16(Bp1 + kt * 32, BsW1);
    __syncthreads();
    v_bf16x8 af[4], bfw[4];
    #pragma unroll
    for (int i = 0; i < 4; i++)
      af[i] = *(const v_bf16x8*)&As[(wm + i * 16 + c) * 32 + quad * 8];
    #pragma unroll
    for (int j = 0; j < 4; j++)
      bfw[j] = *(const v_bf16x8*)&Bs[(wn + j * 16 + c) * 32 + quad * 8];
    #pragma unroll
    for (int i = 0; i < 4; i++)
      #pragma unroll
      for (int j = 0; j < 4; j++)
        acc[i][j] = __builtin_amdgcn_mfma_f32_16x16x32_bf16(af[i], bfw[j], acc[i][j], 0, 0, 0);
    __syncthreads();
  }

  if (VT && n0 >= 2048) {  // V region: write transposed into VtG[(b*NH+h)*64+d][t]
    #pragma unroll
    for (int i = 0; i < 4; i++)
      #pragma unroll
      for (int j = 0; j < 4; j++) {
        int hcol = n0 + wn + j * 16 + c - 2048;
        int hh = hcol >> 6, dd = hcol & 63;
        int rg0 = m0 + wm + i * 16 + quad * 4;
        int bb = rg0 >> 11, t0 = rg0 & (NT - 1);
        v_u16x4 ov;
        #pragma unroll
        for (int r = 0; r < 4; r++) ov[r] = f2b(acc[i][j][r]);
        *(v_u16x4*)((unsigned short*)VtG + ((size_t)((bb * NH + hh) * 64 + dd)) * NT + t0) = ov;
      }
    return;
  }

  #pragma unroll
  for (int i = 0; i < 4; i++)
    #pragma unroll
    for (int j = 0; j < 4; j++)
      #pragma unroll
      for (int r = 0; r < 4; r++) {
        int rg = m0 + wm + i * 16 + quad * 4 + r;
        int cg = n0 + wn + j * 16 + c;
        size_t idx = (size_t)rg * N + cg;
        float v = acc[i][j][r];
        if (RES) v += res[idx];
        if (OUTF32) ((float*)Cout)[idx] = v;
        else ((bf16*)Cout)[idx] = __float2bfloat16(v);
      }
}

// ---------------- GEMM 64x128 ----------------
template <bool RES, bool OUTF32>
__global__ __launch_bounds__(256) void gemm_bt64_kernel(
    const bf16* __restrict__ A, const bf16* __restrict__ Bw,
    const float* __restrict__ res, void* __restrict__ Cout, int N, int K, int lda) {
  __shared__ alignas(16) bf16 As[64 * 32];
  __shared__ alignas(16) bf16 Bs[128 * 32];
  const int tid = threadIdx.x;
  const int wid = tid >> 6;
  const int lane = tid & 63;
  const int c = lane & 15;
  const int quad = lane >> 4;
  const int m0 = blockIdx.y * 64;
  const int n0 = blockIdx.x * 128;
  const int wm = (wid & 1) * 32;
  const int wn = (wid >> 1) * 64;
  const int srow = tid >> 2;
  const int schunk = tid & 3;

  const bf16* Ap = A + (size_t)(m0 + srow) * lda + schunk * 8;
  const bf16* Bp0 = Bw + (size_t)(n0 + srow) * K + schunk * 8;
  const bf16* Bp1 = Bp0 + (size_t)64 * K;
  bf16* AsW  = As + wid * 512;
  bf16* BsW0 = Bs + wid * 512;
  bf16* BsW1 = Bs + 2048 + wid * 512;

  v_f32x4 acc[2][4];
  #pragma unroll
  for (int i = 0; i < 2; i++)
    #pragma unroll
    for (int j = 0; j < 4; j++)
      #pragma unroll
      for (int r = 0; r < 4; r++) acc[i][j][r] = 0.0f;

  const int nk = K >> 5;
  for (int kt = 0; kt < nk; kt++) {
    gl_lds16(Ap + kt * 32, AsW);
    gl_lds16(Bp0 + kt * 32, BsW0);
    gl_lds16(Bp1 + kt * 32, BsW1);
    __syncthreads();
    v_bf16x8 af[2], bfw[4];
    #pragma unroll
    for (int i = 0; i < 2; i++)
      af[i] = *(const v_bf16x8*)&As[(wm + i * 16 + c) * 32 + quad * 8];
    #pragma unroll
    for (int j = 0; j < 4; j++)
      bfw[j] = *(const v_bf16x8*)&Bs[(wn + j * 16 + c) * 32 + quad * 8];
    #pragma unroll
    for (int i = 0; i < 2; i++)
      #pragma unroll
      for (int j = 0; j < 4; j++)
        acc[i][j] = __builtin_amdgcn_mfma_f32_16x16x32_bf16(af[i], bfw[j], acc[i][j], 0, 0, 0);
    __syncthreads();
  }

  #pragma unroll
  for (int i = 0; i < 2; i++)
    #pragma unroll
    for (int j = 0; j < 4; j++)
      #pragma unroll
      for (int r = 0; r < 4; r++) {
        int rg = m0 + wm + i * 16 + quad * 4 + r;
        int cg = n0 + wn + j * 16 + c;
        size_t idx = (size_t)rg * N + cg;
        float v = acc[i][j][r];
        if (RES) v += res[idx];
        if (OUTF32) ((float*)Cout)[idx] = v;
        else ((bf16*)Cout)[idx] = __float2bfloat16(v);
      }
}

// ---------------- Flash attention, split-K (2 halves), S^T form, register P ----------------
// Partials are additive (no-max softmax): block writes raw O (bf16) and l (f32).
__global__ __launch_bounds__(256) void attn_kernel(const bf16* __restrict__ qkv,
                                                   const bf16* __restrict__ VtG,
                                                   bf16* __restrict__ OP,
                                                   float* __restrict__ L) {
  __shared__ alignas(16) bf16 Qs[64 * 72];
  __shared__ alignas(16) bf16 Ks[64 * 72];
  __shared__ alignas(16) bf16 Vt[64 * 72];
  const int tid = threadIdx.x;
  const int w = tid >> 6;
  const int lane = tid & 63;
  const int c = lane & 15;
  const int quad = lane >> 4;
  const int id = blockIdx.x;          // 2048 blocks: bh(32) x u(64)
  const int bh = id & 31;
  const int u = id >> 5;
  const int half = u >> 5;
  const int v = u & 31;
  const int j0 = v & 7;
  const int qt = (v & 24) | (((v >> 3) & 1) ? (7 - j0) : j0);
  const int b = bh >> 4;
  const int h = bh & 15;
  const int srow = tid >> 2;
  const int schunk = tid & 3;
  const int n = qt + 1;
  const int nh0 = (n + 1) >> 1;
  const int k0 = half ? nh0 : 0;
  const int k1 = half ? n : nh0;

  {  // stage Q tile [64 q][64 d]
    const bf16* src = qkv + (size_t)(b * NT + qt * 64 + srow) * 3072 + h * 64 + schunk * 16;
    *(v_u16x8*)&Qs[srow * 72 + schunk * 16] = *(const v_u16x8*)src;
    *(v_u16x8*)&Qs[srow * 72 + schunk * 16 + 8] = *(const v_u16x8*)(src + 8);
  }
  __syncthreads();
  v_bf16x8 aq0 = *(const v_bf16x8*)&Qs[(w * 16 + c) * 72 + quad * 8];
  v_bf16x8 aq1 = *(const v_bf16x8*)&Qs[(w * 16 + c) * 72 + 32 + quad * 8];

  float l_part = 0.0f;
  v_f32x4 o[4];   // o[jd][r] = O[q=w*16+c][d=jd*16+quad*4+r]
  #pragma unroll
  for (int jd = 0; jd < 4; jd++)
    #pragma unroll
    for (int r = 0; r < 4; r++) o[jd][r] = 0.0f;

  const int qrow = w * 16 + c;

  for (int kt = k0; kt < k1; kt++) {
    {  // stage K [64 k][64 d] and Vt [64 d][64 k]
      const bf16* ksrc = qkv + (size_t)(b * NT + kt * 64 + srow) * 3072 + 1024 + h * 64 + schunk * 16;
      *(v_u16x8*)&Ks[srow * 72 + schunk * 16] = *(const v_u16x8*)ksrc;
      *(v_u16x8*)&Ks[srow * 72 + schunk * 16 + 8] = *(const v_u16x8*)(ksrc + 8);
      const bf16* vsrc = VtG + (size_t)(bh * 64 + srow) * NT + kt * 64 + schunk * 16;
      *(v_u16x8*)&Vt[srow * 72 + schunk * 16] = *(const v_u16x8*)vsrc;
      *(v_u16x8*)&Vt[srow * 72 + schunk * 16 + 8] = *(const v_u16x8*)(vsrc + 8);
    }
    __syncthreads();

    const bool diag = (kt == qt);
    v_bf16x4 pf[4];
    #pragma unroll
    for (int j = 0; j < 4; j++) {
      v_bf16x8 ak0 = *(const v_bf16x8*)&Ks[(j * 16 + c) * 72 + quad * 8];
      v_bf16x8 ak1 = *(const v_bf16x8*)&Ks[(j * 16 + c) * 72 + 32 + quad * 8];
      v_f32x4 z;
      #pragma unroll
      for (int r = 0; r < 4; r++) z[r] = 0.0f;
      z = __builtin_amdgcn_mfma_f32_16x16x32_bf16(ak0, aq0, z, 0, 0, 0);
      z = __builtin_amdgcn_mfma_f32_16x16x32_bf16(ak1, aq1, z, 0, 0, 0);
      v_u16x4 pu;
      #pragma unroll
      for (int r = 0; r < 4; r++) {
        float p = __expf(z[r] * 0.125f);
        if (diag && (j * 16 + quad * 4 + r) > qrow) p = 0.0f;
        l_part += p;
        pu[r] = f2b(p);
      }
      union { v_u16x4 u; v_bf16x4 h; } cv; cv.u = pu;
      pf[j] = cv.h;
    }
    #pragma unroll
    for (int jd = 0; jd < 4; jd++)
      #pragma unroll
      for (int j = 0; j < 4; j++) {
        v_bf16x4 av = *(const v_bf16x4*)&Vt[(jd * 16 + c) * 72 + j * 16 + quad * 4];
        o[jd] = mfma16(av, pf[j], o[jd]);
      }
    __syncthreads();
  }

  float l = l_part;
  l += __shfl_xor(l, 16, 64);
  l += __shfl_xor(l, 32, 64);

  const size_t ti = (size_t)((bh * 32 + qt) * 2 + half);
  if (quad == 0) L[ti * 64 + qrow] = l;
  unsigned short* OPu = (unsigned short*)OP + (ti * 64 + qrow) * 64;
  #pragma unroll
  for (int jd = 0; jd < 4; jd++) {
    v_u16x4 ov;
    #pragma unroll
    for (int r = 0; r < 4; r++) ov[r] = f2b(o[jd][r]);
    *(v_u16x4*)(OPu + jd * 16 + quad * 4) = ov;
  }
}

// ---------------- combine split-K partials -> attnout ----------------
__global__ __launch_bounds__(256) void attn_combine_kernel(
    const bf16* __restrict__ OP, const float* __restrict__ L, bf16* __restrict__ out) {
  const int bq = blockIdx.x;     // bh*32 + qt
  const int bh = bq >> 5, qt = bq & 31;
  const int b = bh >> 4, h = bh & 15;
  const int tid = threadIdx.x;
  const int q = tid >> 2, dg = (tid & 3) * 16;
  const size_t ti0 = (size_t)bq * 2;
  float inv = 1.0f / (L[ti0 * 64 + q] + L[(ti0 + 1) * 64 + q]);
  const unsigned short* O0 = (const unsigned short*)OP + (ti0 * 64 + q) * 64 + dg;
  const unsigned short* O1 = (const unsigned short*)OP + ((ti0 + 1) * 64 + q) * 64 + dg;
  unsigned short* dst = (unsigned short*)out + (size_t)(b * NT + qt * 64 + q) * ND + h * 64 + dg;
  #pragma unroll
  for (int i = 0; i < 16; i += 4) {
    v_u16x4 a = *(const v_u16x4*)(O0 + i);
    v_u16x4 bb = *(const v_u16x4*)(O1 + i);
    v_u16x4 o;
    #pragma unroll
    for (int r = 0; r < 4; r++) o[r] = f2b((b2f(a[r]) + b2f(bb[r])) * inv);
    *(v_u16x4*)(dst + i) = o;
  }
}

// ---------------- fused: rmsnorm2 + zg proj (K=1024) + P2 proj (K=64) + scanprep ----------------
__global__ __launch_bounds__(256) void proj_scan_kernel(
    const float* __restrict__ x1, const float* __restrict__ n2w,
    const bf16* __restrict__ W1, const bf16* __restrict__ W2,
    const float* __restrict__ dt_b,
    float* __restrict__ dt_a, float* __restrict__ dtz_a,
    float* __restrict__ gate_a, float* __restrict__ P2) {
  __shared__ alignas(16) bf16 h2S[16 * 1032];
  __shared__ alignas(16) bf16 Bs[128 * 32];
  __shared__ alignas(16) bf16 zgS[16 * 136];
  const int tid = threadIdx.x;
  const int w = tid >> 6, lane = tid & 63, c = lane & 15, quad = lane >> 4;
  const int m0 = blockIdx.x * 16;
  unsigned short* h2Su = (unsigned short*)h2S;
  unsigned short* zgSu = (unsigned short*)zgS;

  {
    const int r16 = tid >> 4, ct = tid & 15;
    const float* xr = x1 + (size_t)(m0 + r16) * ND + ct * 64;
    v_f32x4 xv[16];
    float ss = 0.0f;
    #pragma unroll
    for (int i = 0; i < 16; i++) {
      xv[i] = *(const v_f32x4*)(xr + i * 4);
      ss += xv[i][0]*xv[i][0] + xv[i][1]*xv[i][1] + xv[i][2]*xv[i][2] + xv[i][3]*xv[i][3];
    }
    ss += __shfl_xor(ss, 1, 64);
    ss += __shfl_xor(ss, 2, 64);
    ss += __shfl_xor(ss, 4, 64);
    ss += __shfl_xor(ss, 8, 64);
    float sc = rsqrtf(ss * (1.0f / ND) + RMS_EPS);
    const float* wr = n2w + ct * 64;
    #pragma unroll
    for (int i = 0; i < 16; i++) {
      v_f32x4 wv = *(const v_f32x4*)(wr + i * 4);
      v_u16x4 o;
      o[0] = f2b(xv[i][0] * sc * wv[0]);
      o[1] = f2b(xv[i][1] * sc * wv[1]);
      o[2] = f2b(xv[i][2] * sc * wv[2]);
      o[3] = f2b(xv[i][3] * sc * wv[3]);
      *(v_u16x4*)&h2Su[r16 * 1032 + ct * 64 + i * 4] = o;
    }
  }
  __syncthreads();

  const int lrow = lane >> 2, lk = lane & 3;
  v_f32x4 acc[2];
  #pragma unroll
  for (int j = 0; j < 2; j++)
    #pragma unroll
    for (int r = 0; r < 4; r++) acc[j][r] = 0.0f;
  for (int kt = 0; kt < 32; kt++) {
    gl_lds16(W1 + (size_t)(w * 32 + lrow) * 1024 + kt * 32 + lk * 8, Bs + (w * 32) * 32);
    gl_lds16(W1 + (size_t)(w * 32 + 16 + lrow) * 1024 + kt * 32 + lk * 8, Bs + (w * 32 + 16) * 32);
    __syncthreads();
    v_bf16x8 af = *(const v_bf16x8*)&h2S[c * 1032 + kt * 32 + quad * 8];
    #pragma unroll
    for (int j = 0; j < 2; j++) {
      v_bf16x8 bfw = *(const v_bf16x8*)&Bs[(w * 32 + j * 16 + c) * 32 + quad * 8];
      acc[j] = __builtin_amdgcn_mfma_f32_16x16x32_bf16(af, bfw, acc[j], 0, 0, 0);
    }
    __syncthreads();
  }
  #pragma unroll
  for (int j = 0; j < 2; j++)
    #pragma unroll
    for (int r = 0; r < 4; r++)
      zgSu[(quad * 4 + r) * 136 + w * 32 + j * 16 + c] = f2b(acc[j][r]);
  __syncthreads();

  v_f32x4 acc2[2];
  #pragma unroll
  for (int j = 0; j < 2; j++)
    #pragma unroll
    for (int r = 0; r < 4; r++) acc2[j][r] = 0.0f;
  for (int kt = 0; kt < 2; kt++) {
    gl_lds16(W2 + (size_t)(w * 32 + lrow) * 64 + kt * 32 + lk * 8, Bs + (w * 32) * 32);
    gl_lds16(W2 + (size_t)(w * 32 + 16 + lrow) * 64 + kt * 32 + lk * 8, Bs + (w * 32 + 16) * 32);
    __syncthreads();
    v_bf16x8 af = *(const v_bf16x8*)&zgS[c * 136 + kt * 32 + quad * 8];
    #pragma unroll
    for (int j = 0; j < 2; j++) {
      v_bf16x8 bfw = *(const v_bf16x8*)&Bs[(w * 32 + j * 16 + c) * 32 + quad * 8];
      acc2[j] = __builtin_amdgcn_mfma_f32_16x16x32_bf16(af, bfw, acc2[j], 0, 0, 0);
    }
    __syncthreads();
  }

  #pragma unroll
  for (int j = 0; j < 2; j++)
    #pragma unroll
    for (int r = 0; r < 4; r++) {
      const int row = quad * 4 + r;
      const int col = w * 32 + j * 16 + c;
      const size_t grow = (size_t)(m0 + row);
      if (w < 2) {
        float z = b2f(zgSu[row * 136 + col]);
        float a = acc2[j][r] + dt_b[col];
        float dt = (a > 20.0f) ? a : log1pf(__expf(a));
        dt_a[grow * NSC + col] = dt;
        dtz_a[grow * NSC + col] = dt * z;
      } else {
        P2[grow * 128 + col] = acc2[j][r];
        float g = b2f(zgSu[row * 136 + col]);
        gate_a[grow * NSC + (col - 64)] = g / (1.0f + __expf(-g));
      }
    }
}

// ---------------- chunked parallel scan ----------------
__global__ __launch_bounds__(256) void scanA_kernel(
    const float* __restrict__ dt_a, const float* __restrict__ dtz_a,
    const float* __restrict__ P2, const float* __restrict__ A_log,
    float* __restrict__ Pbuf, float* __restrict__ Sbuf) {
  __shared__ float dtS[CLEN * 16], dtzS[CLEN * 16], biS[CLEN * 16];
  const int k = blockIdx.x, scg = blockIdx.y, b = blockIdx.z;
  const int tid = threadIdx.x;
  const int t0 = k * CLEN;
  {
    int r = tid >> 2, c4 = (tid & 3) * 4;
    *(v_f32x4*)&dtS[r * 16 + c4]  = *(const v_f32x4*)&dt_a[(size_t)(b * NT + t0 + r) * NSC + scg * 16 + c4];
    *(v_f32x4*)&dtzS[r * 16 + c4] = *(const v_f32x4*)&dtz_a[(size_t)(b * NT + t0 + r) * NSC + scg * 16 + c4];
    *(v_f32x4*)&biS[r * 16 + c4]  = *(const v_f32x4*)&P2[(size_t)(b * NT + t0 + r) * 128 + 64 + c4];
  }
  __syncthreads();
  const int st = tid & 15, scl = tid >> 4;
  const float A = -__expf(A_log[(scg * 16 + scl) * NST + st]);
  float P = 1.0f, s = 0.0f;
  #pragma unroll
  for (int t = 0; t < CLEN; t++) {
    float a = fmaf(dtS[t * 16 + scl], A, 1.0f);
    float u = dtzS[t * 16 + scl] * biS[t * 16 + st];
    P *= a;
    s = fmaf(a, s, u);
  }
  size_t idx = (size_t)(b * NCHUNK + k) * 1024 + scg * 256 + tid;
  Pbuf[idx] = P;
  Sbuf[idx] = s;
}

__global__ __launch_bounds__(256) void scanC_kernel(
    const float* __restrict__ dt_a, const float* __restrict__ dtz_a,
    const float* __restrict__ P2, const float* __restrict__ gate_a,
    const float* __restrict__ A_log, const float* __restrict__ Pbuf,
    const float* __restrict__ Sbuf, bf16* __restrict__ ys) {
  __shared__ float dtS[CLEN * 16], dtzS[CLEN * 16], biS[CLEN * 16], ciS[CLEN * 16], gS[CLEN * 16];
  const int k = blockIdx.x, scg = blockIdx.y, b = blockIdx.z;
  const int tid = threadIdx.x;
  const int t0 = k * CLEN;
  {
    int r = tid >> 2, c4 = (tid & 3) * 4;
    *(v_f32x4*)&dtS[r * 16 + c4]  = *(const v_f32x4*)&dt_a[(size_t)(b * NT + t0 + r) * NSC + scg * 16 + c4];
    *(v_f32x4*)&dtzS[r * 16 + c4] = *(const v_f32x4*)&dtz_a[(size_t)(b * NT + t0 + r) * NSC + scg * 16 + c4];
    *(v_f32x4*)&biS[r * 16 + c4]  = *(const v_f32x4*)&P2[(size_t)(b * NT + t0 + r) * 128 + 64 + c4];
    *(v_f32x4*)&ciS[r * 16 + c4]  = *(const v_f32x4*)&P2[(size_t)(b * NT + t0 + r) * 128 + 80 + c4];
    *(v_f32x4*)&gS[r * 16 + c4]   = *(const v_f32x4*)&gate_a[(size_t)(b * NT + t0 + r) * NSC + scg * 16 + c4];
  }
  const int st = tid & 15, scl = tid >> 4;
  const float A = -__expf(A_log[(scg * 16 + scl) * NST + st]);
  float s = 0.0f;
  for (int kk = 0; kk < k; kk++) {
    size_t idx = (size_t)(b * NCHUNK + kk) * 1024 + scg * 256 + tid;
    s = fmaf(Pbuf[idx], s, Sbuf[idx]);
  }
  __syncthreads();
  for (int t = 0; t < CLEN; t++) {
    float a = fmaf(dtS[t * 16 + scl], A, 1.0f);
    float u = dtzS[t * 16 + scl] * biS[t * 16 + st];
    s = fmaf(a, s, u);
    float pv = s * ciS[t * 16 + st];
    pv += __shfl_xor(pv, 1, 64);
    pv += __shfl_xor(pv, 2, 64);
    pv += __shfl_xor(pv, 4, 64);
    pv += __shfl_xor(pv, 8, 64);
    if (st == 0)
      ys[(size_t)(b * NT + t0 + t) * NSC + scg * 16 + scl] = __float2bfloat16(pv * gS[t * 16 + scl]);
  }
}

extern "C" void kernel_launch(void* const* d_in, const int* in_sizes, int n_in,
                              void* d_out, int out_size, void* d_ws, size_t ws_size,
                              hipStream_t stream) {
  const float* x      = (const float*)d_in[0];
  const float* qkv_w  = (const float*)d_in[1];
  const float* o_w    = (const float*)d_in[2];
  const float* n1w    = (const float*)d_in[3];
  const float* n2w    = (const float*)d_in[4];
  const float* in_w   = (const float*)d_in[5];
  const float* out_w  = (const float*)d_in[6];
  const float* A_log  = (const float*)d_in[7];
  const float* Bp_w   = (const float*)d_in[8];
  const float* Cp_w   = (const float*)d_in[9];
  const float* dt_w   = (const float*)d_in[10];
  const float* dt_b   = (const float*)d_in[11];
  const float* gate_w = (const float*)d_in[12];
  float* out = (float*)d_out;

  char* ws = (char*)d_ws;
  size_t off = 0;
  auto alloc = [&](size_t bytes) {
    char* p = ws + off;
    off += (bytes + 255) & ~(size_t)255;
    return p;
  };
  bf16* qkvw_b = (bf16*)alloc((size_t)3 * ND * ND * 2);
  bf16* ow_b   = (bf16*)alloc((size_t)ND * ND * 2);
  bf16* outw_b = (bf16*)alloc((size_t)ND * NSC * 2);
  bf16* W1     = (bf16*)alloc((size_t)128 * ND * 2);
  bf16* W2     = (bf16*)alloc((size_t)128 * NSC * 2);
  char* region0 = alloc((size_t)NM * 3 * ND * 2);         // qkv bf16 -> x1 f32
  char* region1 = alloc((size_t)NM * ND * 2);             // h -> attnout
  bf16* VtG    = (bf16*)alloc((size_t)NB * NH * 64 * NT * 2);
  float* P2    = (float*)alloc((size_t)NM * 128 * 4);
  float* dt_a  = (float*)alloc((size_t)NM * NSC * 4);
  float* dtz_a = (float*)alloc((size_t)NM * NSC * 4);
  float* gate_a= (float*)alloc((size_t)NM * NSC * 4);
  bf16*  ys    = (bf16*)alloc((size_t)NM * NSC * 2);
  float* Pbuf  = (float*)alloc((size_t)NB * NCHUNK * 1024 * 4);
  float* Sbuf  = (float*)alloc((size_t)NB * NCHUNK * 1024 * 4);
  bf16*  OP    = (bf16*)alloc((size_t)2048 * 64 * 64 * 2);   // 16 MB split-K partial O
  float* Lb    = (float*)alloc((size_t)2048 * 64 * 4);       // 512 KB partial l

  bf16*  qkv     = (bf16*)region0;
  float* x1      = (float*)region0;   // aliases qkv (dead after attn)
  bf16*  h       = (bf16*)region1;
  bf16*  attnout = (bf16*)region1;    // aliases h (dead after qkv gemm)

  cvt_rms_kernel<<<4295 + NM, 256, 0, stream>>>(qkv_w, o_w, out_w, in_w, gate_w, dt_w,
                                                Bp_w, Cp_w, qkvw_b, ow_b, outw_b, W1, W2,
                                                x, n1w, h);
  gemm_bt_kernel<false, false, true><<<dim3(3 * ND / 128, NM / 128), 256, 0, stream>>>(
      h, qkvw_b, nullptr, (void*)qkv, 3 * ND, ND, ND, VtG);
  attn_kernel<<<2048, 256, 0, stream>>>(qkv, VtG, OP, Lb);
  attn_combine_kernel<<<1024, 256, 0, stream>>>(OP, Lb, attnout);
  gemm_bt64_kernel<true, true><<<dim3(ND / 128, NM / 64), 256, 0, stream>>>(
      attnout, ow_b, x, (void*)x1, ND, ND, ND);
  proj_scan_kernel<<<NM / 16, 256, 0, stream>>>(x1, n2w, W1, W2, dt_b,
                                                dt_a, dtz_a, gate_a, P2);
  scanA_kernel<<<dim3(NCHUNK, 4, NB), 256, 0, stream>>>(dt_a, dtz_a, P2, A_log, Pbuf, Sbuf);
  scanC_kernel<<<dim3(NCHUNK, 4, NB), 256, 0, stream>>>(dt_a, dtz_a, P2, gate_a, A_log,
                                                        Pbuf, Sbuf, ys);
  gemm_bt64_kernel<true, true><<<dim3(ND / 128, NM / 64), 256, 0, stream>>>(
      ys, outw_b, x1, (void*)out, ND, NSC, NSC);
}

// Round 10
// 267.653 us; speedup vs baseline: 1.0156x; 1.0156x over previous
//
#include <hip/hip_runtime.h>
#include <hip/hip_bf16.h>
#include <math.h>

typedef __hip_bfloat16 bf16;
typedef __attribute__((ext_vector_type(4))) float v_f32x4;
typedef __attribute__((ext_vector_type(4))) unsigned short v_u16x4;
typedef __attribute__((ext_vector_type(8))) unsigned short v_u16x8;
typedef __attribute__((ext_vector_type(8))) __bf16 v_bf16x8;
typedef __attribute__((ext_vector_type(4))) __bf16 v_bf16x4;
typedef __attribute__((ext_vector_type(4))) short v_s16x4;

#define NB 2
#define NT 2048
#define ND 1024
#define NH 16
#define NSC 64
#define NST 16
#define NM (NB*NT)
#define RMS_EPS 1.1920929e-07f
#define NCHUNK 32
#define CLEN 64

__device__ inline float b2f(unsigned short u) {
  union { unsigned int i; float f; } v; v.i = ((unsigned int)u) << 16; return v.f;
}
__device__ inline unsigned short f2b(float f) {  // RNE f32->bf16
  union { float f; unsigned int i; } v; v.f = f;
  unsigned int r = (v.i + 0x7FFF + ((v.i >> 16) & 1)) >> 16;
  return (unsigned short)r;
}

// K=16 bf16 MFMA with builtin-name fallback
__device__ inline v_f32x4 mfma16(v_bf16x4 a, v_bf16x4 b, v_f32x4 c) {
#if __has_builtin(__builtin_amdgcn_mfma_f32_16x16x16_bf16)
  return __builtin_amdgcn_mfma_f32_16x16x16_bf16(a, b, c, 0, 0, 0);
#else
  union U { v_bf16x4 h; v_s16x4 s; };
  U ua, ub; ua.h = a; ub.h = b;
  return __builtin_amdgcn_mfma_f32_16x16x16bf16_1k(ua.s, ub.s, c, 0, 0, 0);
#endif
}

// async global->LDS, 16B per lane; LDS dest = wave-uniform base + lane*16
__device__ inline void gl_lds16(const bf16* g, bf16* l) {
  __builtin_amdgcn_global_load_lds((__attribute__((address_space(1))) void*)g,
                                   (__attribute__((address_space(3))) void*)l,
                                   16, 0, 0);
}

// ---------------- fused: all weight cvt (blocks 0..4294) + rmsnorm1 (blocks 4295..8390) ----------------
__global__ __launch_bounds__(256) void cvt_rms_kernel(
    const float* __restrict__ qkv_w, const float* __restrict__ o_w,
    const float* __restrict__ out_w, const float* __restrict__ in_w,
    const float* __restrict__ gate_w, const float* __restrict__ dt_w,
    const float* __restrict__ Bp_w, const float* __restrict__ Cp_w,
    bf16* __restrict__ qkvw_b, bf16* __restrict__ ow_b, bf16* __restrict__ outw_b,
    bf16* __restrict__ W1, bf16* __restrict__ W2,
    const float* __restrict__ x, const float* __restrict__ n1w, bf16* __restrict__ h) {
  const int blk = blockIdx.x, t = threadIdx.x;
  if (blk >= 4295) {  // rmsnorm1 of x row -> h
    const int row = blk - 4295;
    v_f32x4 xv = *(const v_f32x4*)(x + (size_t)row * ND + t * 4);
    float s = xv[0]*xv[0] + xv[1]*xv[1] + xv[2]*xv[2] + xv[3]*xv[3];
    #pragma unroll
    for (int off = 32; off; off >>= 1) s += __shfl_xor(s, off, 64);
    __shared__ float red[4];
    __shared__ float scale_s;
    if ((t & 63) == 0) red[t >> 6] = s;
    __syncthreads();
    if (t == 0) scale_s = rsqrtf((red[0] + red[1] + red[2] + red[3]) * (1.0f / ND) + RMS_EPS);
    __syncthreads();
    float sc = scale_s;
    v_f32x4 wv = *(const v_f32x4*)(n1w + t * 4);
    v_u16x4 o;
    o[0] = f2b(xv[0] * sc * wv[0]);
    o[1] = f2b(xv[1] * sc * wv[1]);
    o[2] = f2b(xv[2] * sc * wv[2]);
    o[3] = f2b(xv[3] * sc * wv[3]);
    *(v_u16x4*)((unsigned short*)h + (size_t)row * ND + t * 4) = o;
    return;
  }
  const float* src; bf16* dst; int base;
  if (blk < 3072)      { src = qkv_w;  dst = qkvw_b;      base = blk; }
  else if (blk < 4096) { src = o_w;    dst = ow_b;        base = blk - 3072; }
  else if (blk < 4160) { src = out_w;  dst = outw_b;      base = blk - 4096; }
  else if (blk < 4224) { src = in_w;   dst = W1;          base = blk - 4160; }
  else if (blk < 4288) { src = gate_w; dst = W1 + 65536;  base = blk - 4224; }
  else if (blk < 4292) { src = dt_w;   dst = W2;          base = blk - 4288; }
  else if (blk == 4292){ src = Bp_w;   dst = W2 + 4096;   base = 0; }
  else if (blk == 4293){ src = Cp_w;   dst = W2 + 5120;   base = 0; }
  else {  // zero tail of W2 (rows 96..127)
    v_u16x8 z;
    #pragma unroll
    for (int i = 0; i < 8; i++) z[i] = 0;
    *(v_u16x8*)(W2 + 6144 + t * 8) = z;
    return;
  }
  int i = base * 256 + t;
  v_f32x4 v = ((const v_f32x4*)src)[i];
  v_u16x4 o;
  o[0] = f2b(v[0]); o[1] = f2b(v[1]); o[2] = f2b(v[2]); o[3] = f2b(v[3]);
  ((v_u16x4*)dst)[i] = o;
}

// ---------------- GEMM 128x128; VT=true: V-region blocks write VtG transposed ----------------
template <bool RES, bool OUTF32, bool VT>
__global__ __launch_bounds__(256) void gemm_bt_kernel(
    const bf16* __restrict__ A, const bf16* __restrict__ Bw,
    const float* __restrict__ res, void* __restrict__ Cout, int N, int K, int lda,
    bf16* __restrict__ VtG) {
  __shared__ alignas(16) bf16 As[128 * 32];
  __shared__ alignas(16) bf16 Bs[128 * 32];
  const int tid = threadIdx.x;
  const int wid = tid >> 6;
  const int lane = tid & 63;
  const int c = lane & 15;
  const int quad = lane >> 4;
  const int m0 = blockIdx.y * 128;
  const int n0 = blockIdx.x * 128;
  const int wm = (wid >> 1) * 64;
  const int wn = (wid & 1) * 64;
  const int srow = tid >> 2;
  const int schunk = tid & 3;

  const bf16* Ap0 = A + (size_t)(m0 + srow) * lda + schunk * 8;
  const bf16* Ap1 = Ap0 + (size_t)64 * lda;
  const bf16* Bp0 = Bw + (size_t)(n0 + srow) * K + schunk * 8;
  const bf16* Bp1 = Bp0 + (size_t)64 * K;
  bf16* AsW0 = As + wid * 512;
  bf16* AsW1 = As + 2048 + wid * 512;
  bf16* BsW0 = Bs + wid * 512;
  bf16* BsW1 = Bs + 2048 + wid * 512;

  v_f32x4 acc[4][4];
  #pragma unroll
  for (int i = 0; i < 4; i++)
    #pragma unroll
    for (int j = 0; j < 4; j++)
      #pragma unroll
      for (int r = 0; r < 4; r++) acc[i][j][r] = 0.0f;

  const int nk = K >> 5;
  for (int kt = 0; kt < nk; kt++) {
    gl_lds16(Ap0 + kt * 32, AsW0);
    gl_lds16(Ap1 + kt * 32, AsW1);
    gl_lds16(Bp0 + kt * 32, BsW0);
    gl_lds16(Bp1 + kt * 32, BsW1);
    __syncthreads();
    v_bf16x8 af[4], bfw[4];
    #pragma unroll
    for (int i = 0; i < 4; i++)
      af[i] = *(const v_bf16x8*)&As[(wm + i * 16 + c) * 32 + quad * 8];
    #pragma unroll
    for (int j = 0; j < 4; j++)
      bfw[j] = *(const v_bf16x8*)&Bs[(wn + j * 16 + c) * 32 + quad * 8];
    #pragma unroll
    for (int i = 0; i < 4; i++)
      #pragma unroll
      for (int j = 0; j < 4; j++)
        acc[i][j] = __builtin_amdgcn_mfma_f32_16x16x32_bf16(af[i], bfw[j], acc[i][j], 0, 0, 0);
    __syncthreads();
  }

  if (VT && n0 >= 2048) {  // V region: write transposed into VtG[(b*NH+h)*64+d][t]
    #pragma unroll
    for (int i = 0; i < 4; i++)
      #pragma unroll
      for (int j = 0; j < 4; j++) {
        int hcol = n0 + wn + j * 16 + c - 2048;
        int hh = hcol >> 6, dd = hcol & 63;
        int rg0 = m0 + wm + i * 16 + quad * 4;
        int bb = rg0 >> 11, t0 = rg0 & (NT - 1);
        v_u16x4 ov;
        #pragma unroll
        for (int r = 0; r < 4; r++) ov[r] = f2b(acc[i][j][r]);
        *(v_u16x4*)((unsigned short*)VtG + ((size_t)((bb * NH + hh) * 64 + dd)) * NT + t0) = ov;
      }
    return;
  }

  #pragma unroll
  for (int i = 0; i < 4; i++)
    #pragma unroll
    for (int j = 0; j < 4; j++)
      #pragma unroll
      for (int r = 0; r < 4; r++) {
        int rg = m0 + wm + i * 16 + quad * 4 + r;
        int cg = n0 + wn + j * 16 + c;
        size_t idx = (size_t)rg * N + cg;
        float v = acc[i][j][r];
        if (RES) v += res[idx];
        if (OUTF32) ((float*)Cout)[idx] = v;
        else ((bf16*)Cout)[idx] = __float2bfloat16(v);
      }
}

// ---------------- GEMM 64x128 ----------------
template <bool RES, bool OUTF32>
__global__ __launch_bounds__(256) void gemm_bt64_kernel(
    const bf16* __restrict__ A, const bf16* __restrict__ Bw,
    const float* __restrict__ res, void* __restrict__ Cout, int N, int K, int lda) {
  __shared__ alignas(16) bf16 As[64 * 32];
  __shared__ alignas(16) bf16 Bs[128 * 32];
  const int tid = threadIdx.x;
  const int wid = tid >> 6;
  const int lane = tid & 63;
  const int c = lane & 15;
  const int quad = lane >> 4;
  const int m0 = blockIdx.y * 64;
  const int n0 = blockIdx.x * 128;
  const int wm = (wid & 1) * 32;
  const int wn = (wid >> 1) * 64;
  const int srow = tid >> 2;
  const int schunk = tid & 3;

  const bf16* Ap = A + (size_t)(m0 + srow) * lda + schunk * 8;
  const bf16* Bp0 = Bw + (size_t)(n0 + srow) * K + schunk * 8;
  const bf16* Bp1 = Bp0 + (size_t)64 * K;
  bf16* AsW  = As + wid * 512;
  bf16* BsW0 = Bs + wid * 512;
  bf16* BsW1 = Bs + 2048 + wid * 512;

  v_f32x4 acc[2][4];
  #pragma unroll
  for (int i = 0; i < 2; i++)
    #pragma unroll
    for (int j = 0; j < 4; j++)
      #pragma unroll
      for (int r = 0; r < 4; r++) acc[i][j][r] = 0.0f;

  const int nk = K >> 5;
  for (int kt = 0; kt < nk; kt++) {
    gl_lds16(Ap + kt * 32, AsW);
    gl_lds16(Bp0 + kt * 32, BsW0);
    gl_lds16(Bp1 + kt * 32, BsW1);
    __syncthreads();
    v_bf16x8 af[2], bfw[4];
    #pragma unroll
    for (int i = 0; i < 2; i++)
      af[i] = *(const v_bf16x8*)&As[(wm + i * 16 + c) * 32 + quad * 8];
    #pragma unroll
    for (int j = 0; j < 4; j++)
      bfw[j] = *(const v_bf16x8*)&Bs[(wn + j * 16 + c) * 32 + quad * 8];
    #pragma unroll
    for (int i = 0; i < 2; i++)
      #pragma unroll
      for (int j = 0; j < 4; j++)
        acc[i][j] = __builtin_amdgcn_mfma_f32_16x16x32_bf16(af[i], bfw[j], acc[i][j], 0, 0, 0);
    __syncthreads();
  }

  #pragma unroll
  for (int i = 0; i < 2; i++)
    #pragma unroll
    for (int j = 0; j < 4; j++)
      #pragma unroll
      for (int r = 0; r < 4; r++) {
        int rg = m0 + wm + i * 16 + quad * 4 + r;
        int cg = n0 + wn + j * 16 + c;
        size_t idx = (size_t)rg * N + cg;
        float v = acc[i][j][r];
        if (RES) v += res[idx];
        if (OUTF32) ((float*)Cout)[idx] = v;
        else ((bf16*)Cout)[idx] = __float2bfloat16(v);
      }
}

// ---------------- Flash attention: Q-tile 128 (2 query groups/wave), split-K, register P ----------------
// K/Vt fragments read from LDS ONCE per iter, reused for both query groups ->
// LDS traffic per query halved vs r8. Q lives in registers (staged via Ks/Vt).
__global__ __launch_bounds__(256) void attn_kernel(const bf16* __restrict__ qkv,
                                                   const bf16* __restrict__ VtG,
                                                   bf16* __restrict__ OP,
                                                   float* __restrict__ L) {
  __shared__ alignas(16) bf16 Ks[64 * 72];
  __shared__ alignas(16) bf16 Vt[64 * 72];
  const int tid = threadIdx.x;
  const int w = tid >> 6;
  const int lane = tid & 63;
  const int c = lane & 15;
  const int quad = lane >> 4;
  const int id = blockIdx.x;          // 1024 blocks: bh(32) x u(32)
  const int bh = id & 31;
  const int u = id >> 5;              // 0..31
  const int half = u >> 4;
  const int v = u & 15;
  const int qt2 = (v & 8) ? (15 - (v & 7)) : (v & 7);  // snake -> 34 iters/CU constant
  const int b = bh >> 4;
  const int h = bh & 15;
  const int srow = tid >> 2;
  const int schunk = tid & 3;
  const int qbase = qt2 * 128;
  const int n = 2 * qt2 + 2;          // key tiles (even -> halves equal)
  const int k0 = half ? (qt2 + 1) : 0;
  const int k1 = half ? n : (qt2 + 1);

  {  // stage Q: group0 -> Ks, group1 -> Vt (temporarily)
    const bf16* s0 = qkv + (size_t)(b * NT + qbase + srow) * 3072 + h * 64 + schunk * 16;
    *(v_u16x8*)&Ks[srow * 72 + schunk * 16] = *(const v_u16x8*)s0;
    *(v_u16x8*)&Ks[srow * 72 + schunk * 16 + 8] = *(const v_u16x8*)(s0 + 8);
    const bf16* s1 = qkv + (size_t)(b * NT + qbase + 64 + srow) * 3072 + h * 64 + schunk * 16;
    *(v_u16x8*)&Vt[srow * 72 + schunk * 16] = *(const v_u16x8*)s1;
    *(v_u16x8*)&Vt[srow * 72 + schunk * 16 + 8] = *(const v_u16x8*)(s1 + 8);
  }
  __syncthreads();
  v_bf16x8 aq[2][2];
  aq[0][0] = *(const v_bf16x8*)&Ks[(w * 16 + c) * 72 + quad * 8];
  aq[0][1] = *(const v_bf16x8*)&Ks[(w * 16 + c) * 72 + 32 + quad * 8];
  aq[1][0] = *(const v_bf16x8*)&Vt[(w * 16 + c) * 72 + quad * 8];
  aq[1][1] = *(const v_bf16x8*)&Vt[(w * 16 + c) * 72 + 32 + quad * 8];
  __syncthreads();

  float l_part[2] = {0.0f, 0.0f};
  v_f32x4 o[2][4];   // o[g][jd][r] = O[q = qbase+g*64+w*16+c][d = jd*16+quad*4+r]
  #pragma unroll
  for (int g = 0; g < 2; g++)
    #pragma unroll
    for (int jd = 0; jd < 4; jd++)
      #pragma unroll
      for (int r = 0; r < 4; r++) o[g][jd][r] = 0.0f;

  const int qrow = w * 16 + c;

  for (int kt = k0; kt < k1; kt++) {
    {  // stage K [64 k][64 d] and Vt [64 d][64 k]
      const bf16* ksrc = qkv + (size_t)(b * NT + kt * 64 + srow) * 3072 + 1024 + h * 64 + schunk * 16;
      *(v_u16x8*)&Ks[srow * 72 + schunk * 16] = *(const v_u16x8*)ksrc;
      *(v_u16x8*)&Ks[srow * 72 + schunk * 16 + 8] = *(const v_u16x8*)(ksrc + 8);
      const bf16* vsrc = VtG + (size_t)(bh * 64 + srow) * NT + kt * 64 + schunk * 16;
      *(v_u16x8*)&Vt[srow * 72 + schunk * 16] = *(const v_u16x8*)vsrc;
      *(v_u16x8*)&Vt[srow * 72 + schunk * 16 + 8] = *(const v_u16x8*)(vsrc + 8);
    }
    __syncthreads();

    const bool have0 = (kt <= 2 * qt2);      // wave-uniform
    const bool diag0 = (kt == 2 * qt2);
    const bool diag1 = (kt == 2 * qt2 + 1);
    v_bf16x4 pf[2][4];
    #pragma unroll
    for (int j = 0; j < 4; j++) {
      v_bf16x8 ak0 = *(const v_bf16x8*)&Ks[(j * 16 + c) * 72 + quad * 8];
      v_bf16x8 ak1 = *(const v_bf16x8*)&Ks[(j * 16 + c) * 72 + 32 + quad * 8];
      if (have0) {
        v_f32x4 z;
        #pragma unroll
        for (int r = 0; r < 4; r++) z[r] = 0.0f;
        z = __builtin_amdgcn_mfma_f32_16x16x32_bf16(ak0, aq[0][0], z, 0, 0, 0);
        z = __builtin_amdgcn_mfma_f32_16x16x32_bf16(ak1, aq[0][1], z, 0, 0, 0);
        v_u16x4 pu;
        #pragma unroll
        for (int r = 0; r < 4; r++) {
          float p = __expf(z[r] * 0.125f);
          if (diag0 && (j * 16 + quad * 4 + r) > qrow) p = 0.0f;
          l_part[0] += p;
          pu[r] = f2b(p);
        }
        union { v_u16x4 uu; v_bf16x4 hh; } cv; cv.uu = pu;
        pf[0][j] = cv.hh;
      }
      {
        v_f32x4 z;
        #pragma unroll
        for (int r = 0; r < 4; r++) z[r] = 0.0f;
        z = __builtin_amdgcn_mfma_f32_16x16x32_bf16(ak0, aq[1][0], z, 0, 0, 0);
        z = __builtin_amdgcn_mfma_f32_16x16x32_bf16(ak1, aq[1][1], z, 0, 0, 0);
        v_u16x4 pu;
        #pragma unroll
        for (int r = 0; r < 4; r++) {
          float p = __expf(z[r] * 0.125f);
          if (diag1 && (j * 16 + quad * 4 + r) > qrow) p = 0.0f;
          l_part[1] += p;
          pu[r] = f2b(p);
        }
        union { v_u16x4 uu; v_bf16x4 hh; } cv; cv.uu = pu;
        pf[1][j] = cv.hh;
      }
    }
    // PV: av read once, used by both groups
    #pragma unroll
    for (int jd = 0; jd < 4; jd++)
      #pragma unroll
      for (int j = 0; j < 4; j++) {
        v_bf16x4 av = *(const v_bf16x4*)&Vt[(jd * 16 + c) * 72 + j * 16 + quad * 4];
        if (have0) o[0][jd] = mfma16(av, pf[0][j], o[0][jd]);
        o[1][jd] = mfma16(av, pf[1][j], o[1][jd]);
      }
    __syncthreads();
  }

  const size_t ti = (size_t)((bh * 16 + qt2) * 2 + half);
  #pragma unroll
  for (int g = 0; g < 2; g++) {
    float l = l_part[g];
    l += __shfl_xor(l, 16, 64);
    l += __shfl_xor(l, 32, 64);
    if (quad == 0) L[ti * 128 + g * 64 + qrow] = l;
    unsigned short* OPu = (unsigned short*)OP + (ti * 128 + g * 64 + qrow) * 64;
    #pragma unroll
    for (int jd = 0; jd < 4; jd++) {
      v_u16x4 ov;
      #pragma unroll
      for (int r = 0; r < 4; r++) ov[r] = f2b(o[g][jd][r]);
      *(v_u16x4*)(OPu + jd * 16 + quad * 4) = ov;
    }
  }
}

// ---------------- combine split-K partials -> attnout ----------------
__global__ __launch_bounds__(256) void attn_combine_kernel(
    const bf16* __restrict__ OP, const float* __restrict__ L, bf16* __restrict__ out) {
  const int bq = blockIdx.x;     // bh*16 + qt2   (512 blocks)
  const int bh = bq >> 4, qt2 = bq & 15;
  const int b = bh >> 4, h = bh & 15;
  const int tid = threadIdx.x;
  const int q = tid >> 1;            // 0..127
  const int dg = (tid & 1) * 32;
  const size_t ti0 = (size_t)bq * 2;
  float inv = 1.0f / (L[ti0 * 128 + q] + L[(ti0 + 1) * 128 + q]);
  const unsigned short* O0 = (const unsigned short*)OP + (ti0 * 128 + q) * 64 + dg;
  const unsigned short* O1 = (const unsigned short*)OP + ((ti0 + 1) * 128 + q) * 64 + dg;
  unsigned short* dst = (unsigned short*)out + (size_t)(b * NT + qt2 * 128 + q) * ND + h * 64 + dg;
  #pragma unroll
  for (int i = 0; i < 32; i += 4) {
    v_u16x4 a = *(const v_u16x4*)(O0 + i);
    v_u16x4 bb = *(const v_u16x4*)(O1 + i);
    v_u16x4 o;
    #pragma unroll
    for (int r = 0; r < 4; r++) o[r] = f2b((b2f(a[r]) + b2f(bb[r])) * inv);
    *(v_u16x4*)(dst + i) = o;
  }
}

// ---------------- fused: rmsnorm2 + zg proj (K=1024) + P2 proj (K=64) + scanprep ----------------
__global__ __launch_bounds__(256) void proj_scan_kernel(
    const float* __restrict__ x1, const float* __restrict__ n2w,
    const bf16* __restrict__ W1, const bf16* __restrict__ W2,
    const float* __restrict__ dt_b,
    float* __restrict__ dt_a, float* __restrict__ dtz_a,
    float* __restrict__ gate_a, float* __restrict__ P2) {
  __shared__ alignas(16) bf16 h2S[16 * 1032];
  __shared__ alignas(16) bf16 Bs[128 * 32];
  __shared__ alignas(16) bf16 zgS[16 * 136];
  const int tid = threadIdx.x;
  const int w = tid >> 6, lane = tid & 63, c = lane & 15, quad = lane >> 4;
  const int m0 = blockIdx.x * 16;
  unsigned short* h2Su = (unsigned short*)h2S;
  unsigned short* zgSu = (unsigned short*)zgS;

  {
    const int r16 = tid >> 4, ct = tid & 15;
    const float* xr = x1 + (size_t)(m0 + r16) * ND + ct * 64;
    v_f32x4 xv[16];
    float ss = 0.0f;
    #pragma unroll
    for (int i = 0; i < 16; i++) {
      xv[i] = *(const v_f32x4*)(xr + i * 4);
      ss += xv[i][0]*xv[i][0] + xv[i][1]*xv[i][1] + xv[i][2]*xv[i][2] + xv[i][3]*xv[i][3];
    }
    ss += __shfl_xor(ss, 1, 64);
    ss += __shfl_xor(ss, 2, 64);
    ss += __shfl_xor(ss, 4, 64);
    ss += __shfl_xor(ss, 8, 64);
    float sc = rsqrtf(ss * (1.0f / ND) + RMS_EPS);
    const float* wr = n2w + ct * 64;
    #pragma unroll
    for (int i = 0; i < 16; i++) {
      v_f32x4 wv = *(const v_f32x4*)(wr + i * 4);
      v_u16x4 o;
      o[0] = f2b(xv[i][0] * sc * wv[0]);
      o[1] = f2b(xv[i][1] * sc * wv[1]);
      o[2] = f2b(xv[i][2] * sc * wv[2]);
      o[3] = f2b(xv[i][3] * sc * wv[3]);
      *(v_u16x4*)&h2Su[r16 * 1032 + ct * 64 + i * 4] = o;
    }
  }
  __syncthreads();

  const int lrow = lane >> 2, lk = lane & 3;
  v_f32x4 acc[2];
  #pragma unroll
  for (int j = 0; j < 2; j++)
    #pragma unroll
    for (int r = 0; r < 4; r++) acc[j][r] = 0.0f;
  for (int kt = 0; kt < 32; kt++) {
    gl_lds16(W1 + (size_t)(w * 32 + lrow) * 1024 + kt * 32 + lk * 8, Bs + (w * 32) * 32);
    gl_lds16(W1 + (size_t)(w * 32 + 16 + lrow) * 1024 + kt * 32 + lk * 8, Bs + (w * 32 + 16) * 32);
    __syncthreads();
    v_bf16x8 af = *(const v_bf16x8*)&h2S[c * 1032 + kt * 32 + quad * 8];
    #pragma unroll
    for (int j = 0; j < 2; j++) {
      v_bf16x8 bfw = *(const v_bf16x8*)&Bs[(w * 32 + j * 16 + c) * 32 + quad * 8];
      acc[j] = __builtin_amdgcn_mfma_f32_16x16x32_bf16(af, bfw, acc[j], 0, 0, 0);
    }
    __syncthreads();
  }
  #pragma unroll
  for (int j = 0; j < 2; j++)
    #pragma unroll
    for (int r = 0; r < 4; r++)
      zgSu[(quad * 4 + r) * 136 + w * 32 + j * 16 + c] = f2b(acc[j][r]);
  __syncthreads();

  v_f32x4 acc2[2];
  #pragma unroll
  for (int j = 0; j < 2; j++)
    #pragma unroll
    for (int r = 0; r < 4; r++) acc2[j][r] = 0.0f;
  for (int kt = 0; kt < 2; kt++) {
    gl_lds16(W2 + (size_t)(w * 32 + lrow) * 64 + kt * 32 + lk * 8, Bs + (w * 32) * 32);
    gl_lds16(W2 + (size_t)(w * 32 + 16 + lrow) * 64 + kt * 32 + lk * 8, Bs + (w * 32 + 16) * 32);
    __syncthreads();
    v_bf16x8 af = *(const v_bf16x8*)&zgS[c * 136 + kt * 32 + quad * 8];
    #pragma unroll
    for (int j = 0; j < 2; j++) {
      v_bf16x8 bfw = *(const v_bf16x8*)&Bs[(w * 32 + j * 16 + c) * 32 + quad * 8];
      acc2[j] = __builtin_amdgcn_mfma_f32_16x16x32_bf16(af, bfw, acc2[j], 0, 0, 0);
    }
    __syncthreads();
  }

  #pragma unroll
  for (int j = 0; j < 2; j++)
    #pragma unroll
    for (int r = 0; r < 4; r++) {
      const int row = quad * 4 + r;
      const int col = w * 32 + j * 16 + c;
      const size_t grow = (size_t)(m0 + row);
      if (w < 2) {
        float z = b2f(zgSu[row * 136 + col]);
        float a = acc2[j][r] + dt_b[col];
        float dt = (a > 20.0f) ? a : log1pf(__expf(a));
        dt_a[grow * NSC + col] = dt;
        dtz_a[grow * NSC + col] = dt * z;
      } else {
        P2[grow * 128 + col] = acc2[j][r];
        float g = b2f(zgSu[row * 136 + col]);
        gate_a[grow * NSC + (col - 64)] = g / (1.0f + __expf(-g));
      }
    }
}

// ---------------- chunked parallel scan ----------------
__global__ __launch_bounds__(256) void scanA_kernel(
    const float* __restrict__ dt_a, const float* __restrict__ dtz_a,
    const float* __restrict__ P2, const float* __restrict__ A_log,
    float* __restrict__ Pbuf, float* __restrict__ Sbuf) {
  __shared__ float dtS[CLEN * 16], dtzS[CLEN * 16], biS[CLEN * 16];
  const int k = blockIdx.x, scg = blockIdx.y, b = blockIdx.z;
  const int tid = threadIdx.x;
  const int t0 = k * CLEN;
  {
    int r = tid >> 2, c4 = (tid & 3) * 4;
    *(v_f32x4*)&dtS[r * 16 + c4]  = *(const v_f32x4*)&dt_a[(size_t)(b * NT + t0 + r) * NSC + scg * 16 + c4];
    *(v_f32x4*)&dtzS[r * 16 + c4] = *(const v_f32x4*)&dtz_a[(size_t)(b * NT + t0 + r) * NSC + scg * 16 + c4];
    *(v_f32x4*)&biS[r * 16 + c4]  = *(const v_f32x4*)&P2[(size_t)(b * NT + t0 + r) * 128 + 64 + c4];
  }
  __syncthreads();
  const int st = tid & 15, scl = tid >> 4;
  const float A = -__expf(A_log[(scg * 16 + scl) * NST + st]);
  float P = 1.0f, s = 0.0f;
  #pragma unroll
  for (int t = 0; t < CLEN; t++) {
    float a = fmaf(dtS[t * 16 + scl], A, 1.0f);
    float u = dtzS[t * 16 + scl] * biS[t * 16 + st];
    P *= a;
    s = fmaf(a, s, u);
  }
  size_t idx = (size_t)(b * NCHUNK + k) * 1024 + scg * 256 + tid;
  Pbuf[idx] = P;
  Sbuf[idx] = s;
}

__global__ __launch_bounds__(256) void scanC_kernel(
    const float* __restrict__ dt_a, const float* __restrict__ dtz_a,
    const float* __restrict__ P2, const float* __restrict__ gate_a,
    const float* __restrict__ A_log, const float* __restrict__ Pbuf,
    const float* __restrict__ Sbuf, bf16* __restrict__ ys) {
  __shared__ float dtS[CLEN * 16], dtzS[CLEN * 16], biS[CLEN * 16], ciS[CLEN * 16], gS[CLEN * 16];
  const int k = blockIdx.x, scg = blockIdx.y, b = blockIdx.z;
  const int tid = threadIdx.x;
  const int t0 = k * CLEN;
  {
    int r = tid >> 2, c4 = (tid & 3) * 4;
    *(v_f32x4*)&dtS[r * 16 + c4]  = *(const v_f32x4*)&dt_a[(size_t)(b * NT + t0 + r) * NSC + scg * 16 + c4];
    *(v_f32x4*)&dtzS[r * 16 + c4] = *(const v_f32x4*)&dtz_a[(size_t)(b * NT + t0 + r) * NSC + scg * 16 + c4];
    *(v_f32x4*)&biS[r * 16 + c4]  = *(const v_f32x4*)&P2[(size_t)(b * NT + t0 + r) * 128 + 64 + c4];
    *(v_f32x4*)&ciS[r * 16 + c4]  = *(const v_f32x4*)&P2[(size_t)(b * NT + t0 + r) * 128 + 80 + c4];
    *(v_f32x4*)&gS[r * 16 + c4]   = *(const v_f32x4*)&gate_a[(size_t)(b * NT + t0 + r) * NSC + scg * 16 + c4];
  }
  const int st = tid & 15, scl = tid >> 4;
  const float A = -__expf(A_log[(scg * 16 + scl) * NST + st]);
  float s = 0.0f;
  for (int kk = 0; kk < k; kk++) {
    size_t idx = (size_t)(b * NCHUNK + kk) * 1024 + scg * 256 + tid;
    s = fmaf(Pbuf[idx], s, Sbuf[idx]);
  }
  __syncthreads();
  for (int t = 0; t < CLEN; t++) {
    float a = fmaf(dtS[t * 16 + scl], A, 1.0f);
    float u = dtzS[t * 16 + scl] * biS[t * 16 + st];
    s = fmaf(a, s, u);
    float pv = s * ciS[t * 16 + st];
    pv += __shfl_xor(pv, 1, 64);
    pv += __shfl_xor(pv, 2, 64);
    pv += __shfl_xor(pv, 4, 64);
    pv += __shfl_xor(pv, 8, 64);
    if (st == 0)
      ys[(size_t)(b * NT + t0 + t) * NSC + scg * 16 + scl] = __float2bfloat16(pv * gS[t * 16 + scl]);
  }
}

extern "C" void kernel_launch(void* const* d_in, const int* in_sizes, int n_in,
                              void* d_out, int out_size, void* d_ws, size_t ws_size,
                              hipStream_t stream) {
  const float* x      = (const float*)d_in[0];
  const float* qkv_w  = (const float*)d_in[1];
  const float* o_w    = (const float*)d_in[2];
  const float* n1w    = (const float*)d_in[3];
  const float* n2w    = (const float*)d_in[4];
  const float* in_w   = (const float*)d_in[5];
  const float* out_w  = (const float*)d_in[6];
  const float* A_log  = (const float*)d_in[7];
  const float* Bp_w   = (const float*)d_in[8];
  const float* Cp_w   = (const float*)d_in[9];
  const float* dt_w   = (const float*)d_in[10];
  const float* dt_b   = (const float*)d_in[11];
  const float* gate_w = (const float*)d_in[12];
  float* out = (float*)d_out;

  char* ws = (char*)d_ws;
  size_t off = 0;
  auto alloc = [&](size_t bytes) {
    char* p = ws + off;
    off += (bytes + 255) & ~(size_t)255;
    return p;
  };
  bf16* qkvw_b = (bf16*)alloc((size_t)3 * ND * ND * 2);
  bf16* ow_b   = (bf16*)alloc((size_t)ND * ND * 2);
  bf16* outw_b = (bf16*)alloc((size_t)ND * NSC * 2);
  bf16* W1     = (bf16*)alloc((size_t)128 * ND * 2);
  bf16* W2     = (bf16*)alloc((size_t)128 * NSC * 2);
  char* region0 = alloc((size_t)NM * 3 * ND * 2);         // qkv bf16 -> x1 f32
  char* region1 = alloc((size_t)NM * ND * 2);             // h -> attnout
  bf16* VtG    = (bf16*)alloc((size_t)NB * NH * 64 * NT * 2);
  float* P2    = (float*)alloc((size_t)NM * 128 * 4);
  float* dt_a  = (float*)alloc((size_t)NM * NSC * 4);
  float* dtz_a = (float*)alloc((size_t)NM * NSC * 4);
  float* gate_a= (float*)alloc((size_t)NM * NSC * 4);
  bf16*  ys    = (bf16*)alloc((size_t)NM * NSC * 2);
  float* Pbuf  = (float*)alloc((size_t)NB * NCHUNK * 1024 * 4);
  float* Sbuf  = (float*)alloc((size_t)NB * NCHUNK * 1024 * 4);
  bf16*  OP    = (bf16*)alloc((size_t)1024 * 128 * 64 * 2);  // 16 MB split-K partial O
  float* Lb    = (float*)alloc((size_t)1024 * 128 * 4);      // 512 KB partial l

  bf16*  qkv     = (bf16*)region0;
  float* x1      = (float*)region0;   // aliases qkv (dead after attn)
  bf16*  h       = (bf16*)region1;
  bf16*  attnout = (bf16*)region1;    // aliases h (dead after qkv gemm)

  cvt_rms_kernel<<<4295 + NM, 256, 0, stream>>>(qkv_w, o_w, out_w, in_w, gate_w, dt_w,
                                                Bp_w, Cp_w, qkvw_b, ow_b, outw_b, W1, W2,
                                                x, n1w, h);
  gemm_bt_kernel<false, false, true><<<dim3(3 * ND / 128, NM / 128), 256, 0, stream>>>(
      h, qkvw_b, nullptr, (void*)qkv, 3 * ND, ND, ND, VtG);
  attn_kernel<<<1024, 256, 0, stream>>>(qkv, VtG, OP, Lb);
  attn_combine_kernel<<<512, 256, 0, stream>>>(OP, Lb, attnout);
  gemm_bt64_kernel<true, true><<<dim3(ND / 128, NM / 64), 256, 0, stream>>>(
      attnout, ow_b, x, (void*)x1, ND, ND, ND);
  proj_scan_kernel<<<NM / 16, 256, 0, stream>>>(x1, n2w, W1, W2, dt_b,
                                                dt_a, dtz_a, gate_a, P2);
  scanA_kernel<<<dim3(NCHUNK, 4, NB), 256, 0, stream>>>(dt_a, dtz_a, P2, A_log, Pbuf, Sbuf);
  scanC_kernel<<<dim3(NCHUNK, 4, NB), 256, 0, stream>>>(dt_a, dtz_a, P2, gate_a, A_log,
                                                        Pbuf, Sbuf, ys);
  gemm_bt64_kernel<true, true><<<dim3(ND / 128, NM / 64), 256, 0, stream>>>(
      ys, outw_b, x1, (void*)out, ND, NSC, NSC);
}